// Round 6
// baseline (108.172 us; speedup 1.0000x reference)
//
#include <hip/hip_runtime.h>
#include <hip/hip_fp16.h>
#include <math.h>

#define HEADS 8
#define DIM 32
#define NEG_SLOPE 0.2f

__device__ inline float2 u2f2(unsigned int u) {
    __half2 h = __builtin_bit_cast(__half2, u);
    return __half22float2(h);
}

// Kernel 1: ONE WAVE PER NODE. Lane l loads float4 at row+l*16 (coalesced 1KB).
// Head h=l>>3; dot with per-lane attn fragment; shfl_xor reduce over the 8
// lanes of each head group; fp16 convert + coalesced uint2 write.
__global__ __launch_bounds__(256) void gat_logits_conv_kernel(
    const float4* __restrict__ feat4,    // node row = 64 float4
    const float4* __restrict__ attn_l4,  // 64 float4 (8 heads x 8)
    const float4* __restrict__ attn_r4,
    float* __restrict__ el,
    float* __restrict__ er,
    uint2* __restrict__ feat_h2,         // node row = 64 uint2 (fp16)
    int n_nodes) {
    int wid = (blockIdx.x * blockDim.x + threadIdx.x) >> 6;
    if (wid >= n_nodes) return;
    int lane = threadIdx.x & 63;
    int h = lane >> 3;
    int q = lane & 7;

    float4 al = attn_l4[lane];
    float4 ar = attn_r4[lane];
    float4 v  = feat4[(size_t)wid * 64 + lane];

    float sl = v.x * al.x + v.y * al.y + v.z * al.z + v.w * al.w;
    float sr = v.x * ar.x + v.y * ar.y + v.z * ar.z + v.w * ar.w;
#pragma unroll
    for (int off = 1; off < 8; off <<= 1) {
        sl += __shfl_xor(sl, off, 64);
        sr += __shfl_xor(sr, off, 64);
    }
    if (q == 0) {
        el[wid * HEADS + h] = sl;
        er[wid * HEADS + h] = sr;
    }
    uint2 o;
    o.x = __builtin_bit_cast(unsigned int, __floats2half2_rn(v.x, v.y));
    o.y = __builtin_bit_cast(unsigned int, __floats2half2_rn(v.z, v.w));
    feat_h2[(size_t)wid * 64 + lane] = o;
}

// Kernel 1b: CSR row pointers from sorted dst_idx, edge-parallel.
__global__ void build_rowptr_kernel(const int* __restrict__ dst,
                                    int* __restrict__ rowptr,
                                    int n_edges, int n_nodes) {
    int e = blockIdx.x * blockDim.x + threadIdx.x;
    if (e >= n_edges) return;
    int d = dst[e];
    int prev = (e > 0) ? dst[e - 1] : -1;
    for (int v = prev + 1; v <= d; ++v) rowptr[v] = e;
    if (e == n_edges - 1) {
        for (int v = d + 1; v <= n_nodes; ++v) rowptr[v] = n_edges;
    }
}

// Kernel 2: one WAVE per destination node, 2-deep software-pipelined 8-edge
// batches: batch B's feat/el loads are issued BEFORE batch A is consumed,
// keeping ~16 independent gathers in flight per lane. Predicated tail
// (index clamp + zero weight). No max subtraction (|s| <~ 45 fits f32;
// the softmax ratio is identical).
__global__ __launch_bounds__(256) void gat_aggregate_kernel(
    const uint2* __restrict__ feat_h,    // node row = 64 uint2 (4 halfs/lane)
    const float* __restrict__ el,
    const float* __restrict__ er,
    const int* __restrict__ src_idx,
    const int* __restrict__ rowptr,
    float4* __restrict__ out4,
    int n_nodes) {
    int v = (blockIdx.x * blockDim.x + threadIdx.x) >> 6;
    if (v >= n_nodes) return;
    int lane = threadIdx.x & 63;
    int h = lane >> 3;

    int start = rowptr[v];
    int end   = rowptr[v + 1];
    size_t obase = (size_t)v * 64 + lane;
    if (start == end) {
        out4[obase] = make_float4(0.f, 0.f, 0.f, 0.f);
        return;
    }
    int len = end - start;
    float er_vh = er[v * HEADS + h];

    float denomA = 0.f, denomB = 0.f;
    float4 acc0 = make_float4(0.f, 0.f, 0.f, 0.f);
    float4 acc1 = make_float4(0.f, 0.f, 0.f, 0.f);

    int   idxA[8], idxB[8];
    uint2 frA[8], frB[8];
    float elA[8], elB[8];

#define LOADIDX(IDX, BASE)                                                 \
    _Pragma("unroll")                                                      \
    for (int i = 0; i < 8; ++i) {                                          \
        int e = (BASE) + i;                                                \
        e = e < end ? e : (end - 1);                                       \
        IDX[i] = src_idx[e];                                               \
    }

#define LOADDAT(IDX, FR, EL)                                               \
    _Pragma("unroll")                                                      \
    for (int i = 0; i < 8; ++i) {                                          \
        FR[i] = feat_h[(size_t)IDX[i] * 64 + lane];                        \
        EL[i] = el[(size_t)IDX[i] * HEADS + h];                            \
    }

#define COMPUTE(FR, EL, BASE)                                              \
    _Pragma("unroll")                                                      \
    for (int i = 0; i < 8; ++i) {                                          \
        float s = EL[i] + er_vh;                                           \
        s = s > 0.f ? s : NEG_SLOPE * s;                                   \
        float w = __expf(s);                                               \
        w = ((BASE) + i - start < len) ? w : 0.f;                          \
        if (i & 1) denomB += w; else denomA += w;                          \
        float2 lo = u2f2(FR[i].x);                                         \
        float2 hi = u2f2(FR[i].y);                                         \
        if (i & 1) {                                                       \
            acc1.x += w * lo.x; acc1.y += w * lo.y;                        \
            acc1.z += w * hi.x; acc1.w += w * hi.y;                        \
        } else {                                                           \
            acc0.x += w * lo.x; acc0.y += w * lo.y;                        \
            acc0.z += w * hi.x; acc0.w += w * hi.y;                        \
        }                                                                  \
    }

    // prologue: batch A = edges [start, start+8)
    LOADIDX(idxA, start)
    LOADDAT(idxA, frA, elA)

    for (int k = start; k < end; k += 16) {
        // issue batch B (k+8) loads before consuming A
        LOADIDX(idxB, k + 8)
        LOADDAT(idxB, frB, elB)
        COMPUTE(frA, elA, k)
        // issue next batch A (k+16) loads before consuming B
        LOADIDX(idxA, k + 16)
        LOADDAT(idxA, frA, elA)
        COMPUTE(frB, elB, k + 8)
    }

    float denom = denomA + denomB;
    float inv = 1.f / denom;
    float4 r;
    r.x = acc0.x * inv; r.y = acc0.y * inv;
    r.z = acc0.z * inv; r.w = acc0.w * inv;
    (void)acc1;
    r.x = (acc0.x + 0.f) * inv;  // keep structure simple: combine below
    // combine the two accumulator sets
    r.x = (acc0.x + acc1.x) * inv;
    r.y = (acc0.y + acc1.y) * inv;
    r.z = (acc0.z + acc1.z) * inv;
    r.w = (acc0.w + acc1.w) * inv;
    out4[obase] = r;

#undef LOADIDX
#undef LOADDAT
#undef COMPUTE
}

extern "C" void kernel_launch(void* const* d_in, const int* in_sizes, int n_in,
                              void* d_out, int out_size, void* d_ws, size_t ws_size,
                              hipStream_t stream) {
    const float* feat   = (const float*)d_in[0];
    const float* attn_l = (const float*)d_in[1];
    const float* attn_r = (const float*)d_in[2];
    const int*   src    = (const int*)d_in[3];
    const int*   dst    = (const int*)d_in[4];
    float* out = (float*)d_out;

    int n_edges = in_sizes[3];
    int n_nodes = out_size / (HEADS * DIM);
    int nh = n_nodes * HEADS;

    // Workspace: el[nh] | er[nh] | rowptr[n_nodes+1] | (align) | feat_h[nh*32] fp16
    char* ws = (char*)d_ws;
    float* el = (float*)ws;                       ws += (size_t)nh * 4;
    float* er = (float*)ws;                       ws += (size_t)nh * 4;
    int* rowptr = (int*)ws;                       ws += (size_t)(n_nodes + 1) * 4;
    ws = (char*)(((uintptr_t)ws + 15) & ~(uintptr_t)15);
    uint2* feat_h2 = (uint2*)ws;

    hipLaunchKernelGGL(gat_logits_conv_kernel,
                       dim3((n_nodes + 3) / 4), dim3(256), 0, stream,
                       (const float4*)feat, (const float4*)attn_l,
                       (const float4*)attn_r, el, er, feat_h2, n_nodes);

    hipLaunchKernelGGL(build_rowptr_kernel,
                       dim3((n_edges + 255) / 256), dim3(256), 0, stream,
                       dst, rowptr, n_edges, n_nodes);

    int blocks = (n_nodes + 3) / 4;   // 1 wave per node, 4 per block
    hipLaunchKernelGGL(gat_aggregate_kernel,
                       dim3(blocks), dim3(256), 0, stream,
                       (const uint2*)feat_h2, el, er, src, rowptr, (float4*)out,
                       n_nodes);
}

// Round 7
// 99.224 us; speedup vs baseline: 1.0902x; 1.0902x over previous
//
#include <hip/hip_runtime.h>
#include <hip/hip_fp16.h>
#include <math.h>

#define HEADS 8
#define DIM 32
#define NEG_SLOPE 0.2f

__device__ inline float2 u2f2(unsigned int u) {
    __half2 h = __builtin_bit_cast(__half2, u);
    return __half22float2(h);
}

// Kernel 1: ONE WAVE PER NODE. Lane l loads float4 at row+l*16 (coalesced 1KB).
// Head h=l>>3; dot with per-lane attn fragment; shfl_xor reduce over the 8
// lanes of each head group; fp16 convert + coalesced uint2 write.
__global__ __launch_bounds__(256) void gat_logits_conv_kernel(
    const float4* __restrict__ feat4,    // node row = 64 float4
    const float4* __restrict__ attn_l4,  // 64 float4 (8 heads x 8)
    const float4* __restrict__ attn_r4,
    float* __restrict__ el,
    float* __restrict__ er,
    uint2* __restrict__ feat_h2,         // node row = 64 uint2 (fp16)
    int n_nodes) {
    int wid = (blockIdx.x * blockDim.x + threadIdx.x) >> 6;
    if (wid >= n_nodes) return;
    int lane = threadIdx.x & 63;
    int h = lane >> 3;
    int q = lane & 7;

    float4 al = attn_l4[lane];
    float4 ar = attn_r4[lane];
    float4 v  = feat4[(size_t)wid * 64 + lane];

    float sl = v.x * al.x + v.y * al.y + v.z * al.z + v.w * al.w;
    float sr = v.x * ar.x + v.y * ar.y + v.z * ar.z + v.w * ar.w;
#pragma unroll
    for (int off = 1; off < 8; off <<= 1) {
        sl += __shfl_xor(sl, off, 64);
        sr += __shfl_xor(sr, off, 64);
    }
    if (q == 0) {
        el[wid * HEADS + h] = sl;
        er[wid * HEADS + h] = sr;
    }
    uint2 o;
    o.x = __builtin_bit_cast(unsigned int, __floats2half2_rn(v.x, v.y));
    o.y = __builtin_bit_cast(unsigned int, __floats2half2_rn(v.z, v.w));
    feat_h2[(size_t)wid * 64 + lane] = o;
}

// Kernel 1b: CSR row pointers from sorted dst_idx, edge-parallel.
__global__ void build_rowptr_kernel(const int* __restrict__ dst,
                                    int* __restrict__ rowptr,
                                    int n_edges, int n_nodes) {
    int e = blockIdx.x * blockDim.x + threadIdx.x;
    if (e >= n_edges) return;
    int d = dst[e];
    int prev = (e > 0) ? dst[e - 1] : -1;
    for (int v = prev + 1; v <= d; ++v) rowptr[v] = e;
    if (e == n_edges - 1) {
        for (int v = d + 1; v <= n_nodes; ++v) rowptr[v] = n_edges;
    }
}

// Kernel 2: one WAVE per destination node (R4 structure), with all
// wave-uniform work scalarized: readfirstlane(v) makes rowptr/src_idx loads
// uniform (s_load / SMEM path) and the gather addresses SGPR-base + lane
// offset, eliminating per-lane 64-bit address chains. 32-bit index math
// throughout. Tail handled by index clamp + s=-INF (exp -> 0).
// No max subtraction (|s| <~ 45 fits f32; softmax ratio identical).
__global__ __launch_bounds__(256) void gat_aggregate_kernel(
    const uint2* __restrict__ feat_h,    // node row = 64 uint2 (4 halfs/lane)
    const float* __restrict__ el,
    const float* __restrict__ er,
    const int* __restrict__ src_idx,
    const int* __restrict__ rowptr,
    float4* __restrict__ out4,
    int n_nodes) {
    int vraw = (blockIdx.x * blockDim.x + threadIdx.x) >> 6;
    if (vraw >= n_nodes) return;
    int v = __builtin_amdgcn_readfirstlane(vraw);   // wave-uniform node id
    int lane = threadIdx.x & 63;
    int h = lane >> 3;

    int start = __builtin_amdgcn_readfirstlane(rowptr[v]);
    int end   = __builtin_amdgcn_readfirstlane(rowptr[v + 1]);

    unsigned obase = ((unsigned)v << 6) + (unsigned)lane;
    if (start == end) {
        out4[obase] = make_float4(0.f, 0.f, 0.f, 0.f);
        return;
    }
    int endm1 = end - 1;
    float er_vh = er[((unsigned)v << 3) + h];

    float denomA = 0.f, denomB = 0.f;
    float4 acc0 = make_float4(0.f, 0.f, 0.f, 0.f);
    float4 acc1 = make_float4(0.f, 0.f, 0.f, 0.f);

    for (int e = start; e < end; e += 8) {
        int   idx[8];
        uint2 fr[8];
        float elv[8];
#pragma unroll
        for (int i = 0; i < 8; ++i) {
            int ee = (e + i < endm1) ? (e + i) : endm1;   // scalar clamp
            idx[i] = src_idx[ee];                          // uniform -> s_load
        }
#pragma unroll
        for (int i = 0; i < 8; ++i) {
            fr[i] = feat_h[((unsigned)idx[i] << 6) + (unsigned)lane];
        }
#pragma unroll
        for (int i = 0; i < 8; ++i) {
            elv[i] = el[((unsigned)idx[i] << 3) + (unsigned)h];
        }
#pragma unroll
        for (int i = 0; i < 8; ++i) {
            float s = elv[i] + er_vh;
            s = fmaxf(s, NEG_SLOPE * s);          // leaky relu, 2 instr
            if (e + i > endm1) s = -INFINITY;     // tail slot -> w = 0
            float w = __expf(s);
            float2 lo = u2f2(fr[i].x);
            float2 hi = u2f2(fr[i].y);
            if (i & 1) {
                denomB += w;
                acc1.x += w * lo.x; acc1.y += w * lo.y;
                acc1.z += w * hi.x; acc1.w += w * hi.y;
            } else {
                denomA += w;
                acc0.x += w * lo.x; acc0.y += w * lo.y;
                acc0.z += w * hi.x; acc0.w += w * hi.y;
            }
        }
    }
    float inv = 1.f / (denomA + denomB);
    float4 r;
    r.x = (acc0.x + acc1.x) * inv;
    r.y = (acc0.y + acc1.y) * inv;
    r.z = (acc0.z + acc1.z) * inv;
    r.w = (acc0.w + acc1.w) * inv;
    out4[obase] = r;
}

extern "C" void kernel_launch(void* const* d_in, const int* in_sizes, int n_in,
                              void* d_out, int out_size, void* d_ws, size_t ws_size,
                              hipStream_t stream) {
    const float* feat   = (const float*)d_in[0];
    const float* attn_l = (const float*)d_in[1];
    const float* attn_r = (const float*)d_in[2];
    const int*   src    = (const int*)d_in[3];
    const int*   dst    = (const int*)d_in[4];
    float* out = (float*)d_out;

    int n_edges = in_sizes[3];
    int n_nodes = out_size / (HEADS * DIM);
    int nh = n_nodes * HEADS;

    // Workspace: el[nh] | er[nh] | rowptr[n_nodes+1] | (align) | feat_h[nh*32] fp16
    char* ws = (char*)d_ws;
    float* el = (float*)ws;                       ws += (size_t)nh * 4;
    float* er = (float*)ws;                       ws += (size_t)nh * 4;
    int* rowptr = (int*)ws;                       ws += (size_t)(n_nodes + 1) * 4;
    ws = (char*)(((uintptr_t)ws + 15) & ~(uintptr_t)15);
    uint2* feat_h2 = (uint2*)ws;

    hipLaunchKernelGGL(gat_logits_conv_kernel,
                       dim3((n_nodes + 3) / 4), dim3(256), 0, stream,
                       (const float4*)feat, (const float4*)attn_l,
                       (const float4*)attn_r, el, er, feat_h2, n_nodes);

    hipLaunchKernelGGL(build_rowptr_kernel,
                       dim3((n_edges + 255) / 256), dim3(256), 0, stream,
                       dst, rowptr, n_edges, n_nodes);

    int blocks = (n_nodes + 3) / 4;   // 1 wave per node, 4 per block
    hipLaunchKernelGGL(gat_aggregate_kernel,
                       dim3(blocks), dim3(256), 0, stream,
                       (const uint2*)feat_h2, el, er, src, rowptr, (float4*)out,
                       n_nodes);
}